// Round 1
// 1716.182 us; speedup vs baseline: 1.0925x; 1.0925x over previous
//
#include <hip/hip_runtime.h>
#include <math.h>

#define BATCH   2048
#define IN_DIM  256
#define OUT_DIM 256
#define GRIDN   12   // NUM + 1 + 2K knots
#define NBASIS  8    // NUM + K

// Cox-de Boor, degree 3, 12 knots -> 8 basis values. Matches reference
// b_batch(): indicator then 3 refinement sweeps with nan_to_num guards.
__device__ __forceinline__ void bspline8(float x, const float* __restrict__ t,
                                         float* __restrict__ out) {
    float B[11];
#pragma unroll
    for (int j = 0; j < 11; ++j)
        B[j] = (x >= t[j] && x < t[j + 1]) ? 1.0f : 0.0f;
#pragma unroll
    for (int ki = 1; ki <= 3; ++ki) {
#pragma unroll
        for (int j = 0; j < 11 - ki; ++j) {
            float dl = t[j + ki] - t[j];
            float dr = t[j + ki + 1] - t[j + 1];
            float left  = (dl != 0.0f) ? (x - t[j]) / dl * B[j] : 0.0f;
            float right = (dr != 0.0f) ? (t[j + ki + 1] - x) / dr * B[j + 1] : 0.0f;
            B[j] = left + right;
        }
    }
#pragma unroll
    for (int k = 0; k < NBASIS; ++k) out[k] = B[k];
}

// Prep: coef [i][o][k] -> coef_t [o][k][i]  (k-major so main-loop loads are
// wave-coalesced: fixed (o,k), lane-consecutive i -> contiguous 1KB/instr).
// as_t [o][0][i] = mask*scale_base, as_t [o][1][i] = mask*scale_sp.
__global__ __launch_bounds__(256)
void kan_prep(const float* __restrict__ coef, const float* __restrict__ sb,
              const float* __restrict__ sp, const float* __restrict__ mk,
              float* __restrict__ coef_t, float* __restrict__ as_t) {
    int tid = blockIdx.x * 256 + threadIdx.x;   // [0, 65536)
    int o = tid >> 8, i = tid & 255;
    const float4* src = (const float4*)(coef + ((size_t)i * OUT_DIM + o) * NBASIS);
    float4 c0 = src[0], c1 = src[1];
    float v[NBASIS] = {c0.x, c0.y, c0.z, c0.w, c1.x, c1.y, c1.z, c1.w};
#pragma unroll
    for (int k = 0; k < NBASIS; ++k)
        coef_t[((size_t)o * NBASIS + k) * IN_DIM + i] = v[k];  // coalesced per k
    float m = mk[i * OUT_DIM + o];
    as_t[((size_t)o * 2 + 0) * IN_DIM + i] = m * sb[i * OUT_DIM + o];
    as_t[((size_t)o * 2 + 1) * IN_DIM + i] = m * sp[i * OUT_DIM + o];
}

// Main: block = one batch row. 4 waves x 64 lanes; lane owns i = lane*4..+3,
// wave w owns o = w*64..+63 (covers all 256 i per o -> single-wave y_sum reduce).
template <int MODE>   // 1 = k-major transposed ws layouts, 0 = fallback (original layouts)
__global__ __launch_bounds__(256)
void kan_main(const float* __restrict__ x, const float* __restrict__ grid,
              const float* __restrict__ coef, const float* __restrict__ sb,
              const float* __restrict__ sp, const float* __restrict__ mk,
              const float* __restrict__ coef_t, const float* __restrict__ as_t,
              float* __restrict__ out) {
    const int b    = blockIdx.x;
    const int lane = threadIdx.x & 63;
    const int wv   = threadIdx.x >> 6;
    const int i0   = lane * 4;

    float* ysum     = out;
    float* preacts  = out + (size_t)BATCH * OUT_DIM;
    float* postacts = preacts + (size_t)BATCH * OUT_DIM * IN_DIM;
    float* postspl  = postacts + (size_t)BATCH * OUT_DIM * IN_DIM;

    const float4 xv = *(const float4*)(x + (size_t)b * IN_DIM + i0);
    const float xs[4] = {xv.x, xv.y, xv.z, xv.w};
    float sil[4];
#pragma unroll
    for (int c = 0; c < 4; ++c) sil[c] = xs[c] / (1.0f + __expf(-xs[c]));

    float bsp[4][NBASIS];
#pragma unroll
    for (int c = 0; c < 4; ++c) {
        float t[GRIDN];
        const float* g = grid + (size_t)(i0 + c) * GRIDN;
#pragma unroll
        for (int j = 0; j < GRIDN; ++j) t[j] = g[j];
        bspline8(xs[c], t, bsp[c]);
    }

    const size_t rowB = (size_t)b * OUT_DIM * IN_DIM;

    for (int j = 0; j < 64; ++j) {
        const int o = wv * 64 + j;
        float spl[4], val[4];

        if (MODE == 1) {
            // 8 coalesced 1KB wave loads: coef_t[o][k][i0..i0+3]
            const float* cb = coef_t + (size_t)o * (NBASIS * IN_DIM) + i0;
            float4 q[NBASIS];
#pragma unroll
            for (int k = 0; k < NBASIS; ++k)
                q[k] = *(const float4*)(cb + k * IN_DIM);
            const float* qf = (const float*)q;   // q[k] component c = qf[4k+c]
#pragma unroll
            for (int c = 0; c < 4; ++c) {
                spl[c] = bsp[c][0] * qf[0 * 4 + c] + bsp[c][1] * qf[1 * 4 + c] +
                         bsp[c][2] * qf[2 * 4 + c] + bsp[c][3] * qf[3 * 4 + c] +
                         bsp[c][4] * qf[4 * 4 + c] + bsp[c][5] * qf[5 * 4 + c] +
                         bsp[c][6] * qf[6 * 4 + c] + bsp[c][7] * qf[7 * 4 + c];
            }
            // 2 coalesced loads: as_t[o][0][i] (m*sb), as_t[o][1][i] (m*sp)
            const float* ab = as_t + (size_t)o * (2 * IN_DIM) + i0;
            float4 a0 = *(const float4*)(ab);
            float4 a1 = *(const float4*)(ab + IN_DIM);
            const float a0c[4] = {a0.x, a0.y, a0.z, a0.w};
            const float a1c[4] = {a1.x, a1.y, a1.z, a1.w};
#pragma unroll
            for (int c = 0; c < 4; ++c)
                val[c] = a0c[c] * sil[c] + a1c[c] * spl[c];
        } else {
#pragma unroll
            for (int c = 0; c < 4; ++c) {
                const float4* cp =
                    (const float4*)(coef + ((size_t)(i0 + c) * OUT_DIM + o) * NBASIS);
                float4 c0 = cp[0], c1 = cp[1];
                spl[c] = bsp[c][0] * c0.x + bsp[c][1] * c0.y + bsp[c][2] * c0.z +
                         bsp[c][3] * c0.w + bsp[c][4] * c1.x + bsp[c][5] * c1.y +
                         bsp[c][6] * c1.z + bsp[c][7] * c1.w;
                int idx = (i0 + c) * OUT_DIM + o;
                float m = mk[idx];
                val[c] = (m * sb[idx]) * sil[c] + (m * sp[idx]) * spl[c];
            }
        }

        const size_t ro = rowB + (size_t)o * IN_DIM + i0;
        *(float4*)(preacts + ro)  = xv;
        *(float4*)(postspl + ro)  = make_float4(spl[0], spl[1], spl[2], spl[3]);
        *(float4*)(postacts + ro) = make_float4(val[0], val[1], val[2], val[3]);

        float acc = (val[0] + val[1]) + (val[2] + val[3]);
#pragma unroll
        for (int m = 32; m > 0; m >>= 1) acc += __shfl_xor(acc, m, 64);
        if (lane == 0) ysum[(size_t)b * OUT_DIM + o] = acc;
    }
}

extern "C" void kernel_launch(void* const* d_in, const int* in_sizes, int n_in,
                              void* d_out, int out_size, void* d_ws, size_t ws_size,
                              hipStream_t stream) {
    const float* x    = (const float*)d_in[0];
    const float* grid = (const float*)d_in[1];
    const float* coef = (const float*)d_in[2];
    const float* sb   = (const float*)d_in[3];
    const float* sp   = (const float*)d_in[4];
    const float* mk   = (const float*)d_in[5];
    float* out = (float*)d_out;

    const size_t coef_t_elems = (size_t)IN_DIM * OUT_DIM * NBASIS;   // 524288
    const size_t as_t_elems   = (size_t)IN_DIM * OUT_DIM * 2;        // 131072
    const size_t need = (coef_t_elems + as_t_elems) * sizeof(float); // ~2.62 MB

    if (ws_size >= need) {
        float* coef_t = (float*)d_ws;
        float* as_t   = coef_t + coef_t_elems;
        kan_prep<<<IN_DIM * OUT_DIM / 256, 256, 0, stream>>>(coef, sb, sp, mk, coef_t, as_t);
        kan_main<1><<<BATCH, 256, 0, stream>>>(x, grid, nullptr, nullptr, nullptr, nullptr,
                                               coef_t, as_t, out);
    } else {
        kan_main<0><<<BATCH, 256, 0, stream>>>(x, grid, coef, sb, sp, mk,
                                               nullptr, nullptr, out);
    }
}